// Round 8
// baseline (725.780 us; speedup 1.0000x reference)
//
#include <hip/hip_runtime.h>

constexpr int NN = 100000;   // nodes
constexpr int NE = 1600000;  // edges
constexpr int NG = 5000;     // graphs
constexpr int BKT = 64;      // dst-nodes per bucket
constexpr int NBKT = (NN + BKT - 1) / BKT;   // 1563
constexpr int CAP = 1216;    // slab capacity per bucket (mean 1024, +6 sigma)

// ---- workspace layout (4B words), total 3,952,208 words = 15.81 MB ----
constexpr size_t OFF_G  = 2000000;              // g    [NG*10]
constexpr size_t OFF_CN = OFF_G + 50000;        // cnt  [NBKT] (pad to 1600)
constexpr size_t OFF_SL = OFF_CN + 1600;        // slab [NBKT][CAP]

// ---------------- zero cnt + g ----------------
__global__ __launch_bounds__(256) void k_zero(int* __restrict__ cnt,
                                              float* __restrict__ g) {
  int i = blockIdx.x * 256 + threadIdx.x;
  if (i < 1600) cnt[i] = 0;
  if (i < 50000) g[i] = 0.f;
}

// ---------------- bucket append: dst -> (cnt, slab) in ONE pass ----------------
// Native memory-side int atomics to 1563 counters (~1024 ops each, pipelined).
__global__ __launch_bounds__(256) void k_bucket(const int* __restrict__ ei,
                                                int* __restrict__ cnt,
                                                int* __restrict__ slab) {
  int e = blockIdx.x * 256 + threadIdx.x;
  if (e >= NE) return;
  int d = ei[NE + e];                       // dst, coalesced
  int k = d >> 6;
  int slot = atomicAdd(&cnt[k], 1);         // returning int atomic (native)
  slab[(size_t)k * CAP + slot] = e | ((d & 63) << 24);   // edge id (21b) | dl<<24
}

// ---------------- edge MLP: 20-way j-split, W pinned in 48 VGPRs ----------------
// Lane (ep,jj): ep = edge slot (3/wave, lanes 60-63 idle), jj = output (20).
// Each lane holds W[k][jj] for all k -> zero weight re-fetch in the loop.
// 4 partial accumulators break the fma dependence chain. LDS-tile scatter.
__global__ __launch_bounds__(256, 4) void k_edge(
    const int* __restrict__ ei,
    const float* __restrict__ nattr,
    const float* __restrict__ eattr,
    const float* __restrict__ Wm,
    const float* __restrict__ bm,
    const int* __restrict__ cnt,
    const int* __restrict__ slab,
    float* __restrict__ x) {
  __shared__ float xt[20 * 65];    // padded rows: bank spread
  __shared__ int s_n;
  for (int i = threadIdx.x; i < 20 * 65; i += 256) xt[i] = 0.f;
  if (threadIdx.x == 0) s_n = cnt[blockIdx.x];
  __syncthreads();
  int n = s_n;
  const int* sb = slab + (size_t)blockIdx.x * CAP;
  int nbase = blockIdx.x * BKT;

  int wave = threadIdx.x >> 6;
  int lane = threadIdx.x & 63;
  int ep = lane / 20;              // 0..3 (3 -> idle lane)
  int jj = lane - ep * 20;         // 0..19
  bool act = ep < 3;
  int epc = act ? ep : 0;

  float W[48];                     // resident weights: 48 VGPRs, pinned
#pragma unroll
  for (int k = 0; k < 48; ++k) W[k] = Wm[k * 20 + jj];
#pragma unroll
  for (int k = 0; k < 48; ++k) asm volatile("" : "+v"(W[k]));
  float bj = bm[jj];

  int basew = wave * 3;            // this wave's edge-slot base within bucket
  int iC = basew + epc;
  int pC = 0, sC = 0;
  if (basew < n) {
    pC = sb[min(iC, n - 1)];
    sC = ei[pC & 0xFFFFFF];
  }
  while (basew < n) {
    int basewN = basew + 12;                            // 4 waves x 3 edges
    int iN = basewN + epc;
    int pN = 0, sN = 0;
    if (basewN < n) {                                   // prefetch next chain
      pN = sb[min(iN, n - 1)];
      sN = ei[pN & 0xFFFFFF];
    }

    int e  = pC & 0xFFFFFF;
    int dl = (pC >> 24) & 63;
    const float4* ps = (const float4*)(nattr + (size_t)sC * 16);
    const float4* pd = (const float4*)(nattr + (size_t)(nbase + dl) * 16);
    const float4* pe = (const float4*)(eattr + (size_t)e * 16);
    float4 t0 = ps[0], t1 = ps[1], t2 = ps[2], t3 = ps[3];
    float4 u0 = pd[0], u1 = pd[1], u2 = pd[2], u3 = pd[3];
    float4 v0 = pe[0], v1 = pe[1], v2 = pe[2], v3 = pe[3];

    float a0 = 0.f, a1 = 0.f, a2 = 0.f, a3 = 0.f;       // 4 chains
    a0 = fmaf(t0.x, W[0],  a0); a1 = fmaf(t0.y, W[1],  a1);
    a2 = fmaf(t0.z, W[2],  a2); a3 = fmaf(t0.w, W[3],  a3);
    a0 = fmaf(t1.x, W[4],  a0); a1 = fmaf(t1.y, W[5],  a1);
    a2 = fmaf(t1.z, W[6],  a2); a3 = fmaf(t1.w, W[7],  a3);
    a0 = fmaf(t2.x, W[8],  a0); a1 = fmaf(t2.y, W[9],  a1);
    a2 = fmaf(t2.z, W[10], a2); a3 = fmaf(t2.w, W[11], a3);
    a0 = fmaf(t3.x, W[12], a0); a1 = fmaf(t3.y, W[13], a1);
    a2 = fmaf(t3.z, W[14], a2); a3 = fmaf(t3.w, W[15], a3);
    a0 = fmaf(u0.x, W[16], a0); a1 = fmaf(u0.y, W[17], a1);
    a2 = fmaf(u0.z, W[18], a2); a3 = fmaf(u0.w, W[19], a3);
    a0 = fmaf(u1.x, W[20], a0); a1 = fmaf(u1.y, W[21], a1);
    a2 = fmaf(u1.z, W[22], a2); a3 = fmaf(u1.w, W[23], a3);
    a0 = fmaf(u2.x, W[24], a0); a1 = fmaf(u2.y, W[25], a1);
    a2 = fmaf(u2.z, W[26], a2); a3 = fmaf(u2.w, W[27], a3);
    a0 = fmaf(u3.x, W[28], a0); a1 = fmaf(u3.y, W[29], a1);
    a2 = fmaf(u3.z, W[30], a2); a3 = fmaf(u3.w, W[31], a3);
    a0 = fmaf(v0.x, W[32], a0); a1 = fmaf(v0.y, W[33], a1);
    a2 = fmaf(v0.z, W[34], a2); a3 = fmaf(v0.w, W[35], a3);
    a0 = fmaf(v1.x, W[36], a0); a1 = fmaf(v1.y, W[37], a1);
    a2 = fmaf(v1.z, W[38], a2); a3 = fmaf(v1.w, W[39], a3);
    a0 = fmaf(v2.x, W[40], a0); a1 = fmaf(v2.y, W[41], a1);
    a2 = fmaf(v2.z, W[42], a2); a3 = fmaf(v2.w, W[43], a3);
    a0 = fmaf(v3.x, W[44], a0); a1 = fmaf(v3.y, W[45], a1);
    a2 = fmaf(v3.z, W[46], a2); a3 = fmaf(v3.w, W[47], a3);

    float m = fmaxf(((a0 + a1) + (a2 + a3)) + bj, 0.f);
    bool valid = act && (iC < n);
    if (valid && m > 0.f) atomicAdd(&xt[jj * 65 + dl], m);   // LDS fp atomic

    basew = basewN; iC = iN; pC = pN; sC = sN;
  }
  __syncthreads();

  int nn = min(BKT, NN - nbase);
  float* xo = x + (size_t)nbase * 20;
  for (int idx = threadIdx.x; idx < nn * 20; idx += 256) {   // coalesced stores
    int node = idx / 20;
    int j = idx - node * 20;
    xo[idx] = xt[j * 65 + node];
  }
}

#define ST4(A, B, V) { A[B] = (V).x; A[B+1] = (V).y; A[B+2] = (V).z; A[B+3] = (V).w; }

// ---------------- node MLP + pool to graphs (sorted batch -> LDS partials) ----------------
constexpr int SPAN = 64;   // graphs per 256-node window ~13; fallback covers outliers
__global__ __launch_bounds__(256) void k_node(
    const float* __restrict__ x,
    const int* __restrict__ batch,
    const float* __restrict__ W1,
    const float* __restrict__ b1,
    float* __restrict__ g) {
  __shared__ float gacc[SPAN * 10];
  __shared__ int s_bmin;
  for (int i = threadIdx.x; i < SPAN * 10; i += 256) gacc[i] = 0.f;
  int n0 = blockIdx.x * 256;
  if (threadIdx.x == 0) s_bmin = batch[n0];
  __syncthreads();
  int bmin = s_bmin;
  int n = n0 + threadIdx.x;
  if (n < NN) {
    float xi[20];
    const float4* px = (const float4*)(x + (size_t)n * 20);
    { float4 t0 = px[0], t1 = px[1], t2 = px[2], t3 = px[3], t4 = px[4];
      ST4(xi, 0, t0) ST4(xi, 4, t1) ST4(xi, 8, t2) ST4(xi, 12, t3) ST4(xi, 16, t4) }
    float acc[10];
#pragma unroll
    for (int j = 0; j < 10; ++j) acc[j] = b1[j];
#pragma unroll
    for (int k = 0; k < 20; ++k) {
      float fk = xi[k];
#pragma unroll
      for (int j = 0; j < 10; ++j) acc[j] = fmaf(fk, W1[k * 10 + j], acc[j]);
    }
    int bn = batch[n];
    int d = bn - bmin;
    if (d >= 0 && d < SPAN) {
#pragma unroll
      for (int j = 0; j < 10; ++j) {
        float m = fmaxf(acc[j], 0.f);
        if (m > 0.f) atomicAdd(&gacc[d * 10 + j], m);   // LDS
      }
    } else {
#pragma unroll
      for (int j = 0; j < 10; ++j) {
        float m = fmaxf(acc[j], 0.f);
        if (m > 0.f) unsafeAtomicAdd(&g[(size_t)bn * 10 + j], m);
      }
    }
  }
  __syncthreads();
  int lim = min(SPAN * 10, NG * 10 - bmin * 10);
  float* gp = g + (size_t)bmin * 10;
  for (int idx = threadIdx.x; idx < lim; idx += 256) {
    float v = gacc[idx];
    if (v != 0.f) unsafeAtomicAdd(&gp[idx], v);         // sparse residuals
  }
}

// ---------------- graph MLP ----------------
__global__ __launch_bounds__(256) void k_graph(
    const float* __restrict__ g,
    const float* __restrict__ W2, const float* __restrict__ b2,
    const float* __restrict__ W3, const float* __restrict__ b3,
    float* __restrict__ out) {
  int i = blockIdx.x * 256 + threadIdx.x;
  if (i >= NG) return;
  float gi[10];
  const float2* pg = (const float2*)(g + (size_t)i * 10);
#pragma unroll
  for (int k = 0; k < 5; ++k) { float2 v = pg[k]; gi[2*k] = v.x; gi[2*k+1] = v.y; }
  float o = b3[0];
#pragma unroll
  for (int j = 0; j < 10; ++j) {
    float a = b2[j];
#pragma unroll
    for (int k = 0; k < 10; ++k) a = fmaf(gi[k], W2[k * 10 + j], a);
    o = fmaf(fmaxf(a, 0.f), W3[j], o);
  }
  out[i] = o;
}

extern "C" void kernel_launch(void* const* d_in, const int* in_sizes, int n_in,
                              void* d_out, int out_size, void* d_ws, size_t ws_size,
                              hipStream_t stream) {
  const int*   ei    = (const int*)  d_in[0];
  const float* nattr = (const float*)d_in[1];
  const float* eattr = (const float*)d_in[2];
  const int*   batch = (const int*)  d_in[3];
  const float* Wm    = (const float*)d_in[4];
  const float* bm    = (const float*)d_in[5];
  const float* W1    = (const float*)d_in[6];
  const float* b1    = (const float*)d_in[7];
  const float* W2    = (const float*)d_in[8];
  const float* b2    = (const float*)d_in[9];
  const float* W3    = (const float*)d_in[10];
  const float* b3    = (const float*)d_in[11];

  float* x    = (float*)d_ws;
  float* g    = (float*)d_ws + OFF_G;
  int*   cnt  = (int*)d_ws + OFF_CN;
  int*   slab = (int*)d_ws + OFF_SL;

  k_zero  <<<(50000 + 255) / 256, 256, 0, stream>>>(cnt, g);
  k_bucket<<<(NE + 255) / 256, 256, 0, stream>>>(ei, cnt, slab);
  k_edge  <<<NBKT, 256, 0, stream>>>(ei, nattr, eattr, Wm, bm, cnt, slab, x);
  k_node  <<<(NN + 255) / 256, 256, 0, stream>>>(x, batch, W1, b1, g);
  k_graph <<<(NG + 255) / 256, 256, 0, stream>>>(g, W2, b2, W3, b3, (float*)d_out);
}

// Round 9
// 439.701 us; speedup vs baseline: 1.6506x; 1.6506x over previous
//
#include <hip/hip_runtime.h>

constexpr int NN = 100000;   // nodes
constexpr int NE = 1600000;  // edges
constexpr int NG = 5000;     // graphs
constexpr int BKT = 64;      // dst-nodes per bucket
constexpr int NBKT = (NN + BKT - 1) / BKT;   // 1563
constexpr int NB = 128;      // hist/scatter blocks
constexpr int CHUNK = NE / NB;               // 12500 exact

typedef float v2f __attribute__((ext_vector_type(2)));

// ---- workspace layout (4B words), total ~7.4 MB ----
constexpr size_t OFF_G  = 0;                            // g      [NG*10]
constexpr size_t OFF_BH = 50048;                        // bh     [NB][NBKT]
constexpr size_t OFF_ST = OFF_BH + (size_t)NB * NBKT;   // starts [NBKT+1]
constexpr size_t OFF_PM = OFF_ST + NBKT + 1;            // perm   [NE]

// ---------------- pass A: per-block bucket histogram (+ zero g) ----------------
__global__ __launch_bounds__(256) void k_hist(const int* __restrict__ ei,
                                              int* __restrict__ bh,
                                              float* __restrict__ g) {
  __shared__ int lh[NBKT];
  for (int i = threadIdx.x; i < NBKT; i += 256) lh[i] = 0;
  __syncthreads();
  const int* dstp = ei + NE;
  int s = blockIdx.x * CHUNK;
  for (int i = s + threadIdx.x; i < s + CHUNK; i += 256)
    atomicAdd(&lh[dstp[i] >> 6], 1);                    // LDS int atomic
  int gid = blockIdx.x * 256 + threadIdx.x;             // zero g: 12,500 float4
  if (gid < 12500) ((float4*)g)[gid] = make_float4(0.f, 0.f, 0.f, 0.f);
  __syncthreads();
  int* out = bh + (size_t)blockIdx.x * NBKT;            // block-major: coalesced
  for (int k = threadIdx.x; k < NBKT; k += 256) out[k] = lh[k];
}

// ---------------- pass B1: per-bucket totals (grid-parallel) ----------------
__global__ __launch_bounds__(256) void k_btot(const int* __restrict__ bh,
                                              int* __restrict__ starts) {
  int k = blockIdx.x * 256 + threadIdx.x;
  if (k >= NBKT) return;
  int tot = 0;
  for (int b = 0; b < NB; b += 4) {                     // coalesced: k-consecutive
    int a0 = bh[(size_t)(b    ) * NBKT + k];
    int a1 = bh[(size_t)(b + 1) * NBKT + k];
    int a2 = bh[(size_t)(b + 2) * NBKT + k];
    int a3 = bh[(size_t)(b + 3) * NBKT + k];
    tot += a0 + a1 + a2 + a3;
  }
  starts[k] = tot;
}

// ---------------- pass B2: exclusive scan of 1563 totals ----------------
__global__ __launch_bounds__(1024) void k_sscan(int* __restrict__ starts) {
  __shared__ int s0[1024], s1[1024];
  int t = threadIdx.x;
  int k0 = 2 * t, k1 = 2 * t + 1;
  int tot0 = (k0 < NBKT) ? starts[k0] : 0;
  int tot1 = (k1 < NBKT) ? starts[k1] : 0;
  int ssum = tot0 + tot1;
  int* cur = s0; int* nxt = s1;
  cur[t] = ssum;
  __syncthreads();
  for (int off = 1; off < 1024; off <<= 1) {            // Hillis-Steele inclusive
    int v = cur[t];
    if (t >= off) v += cur[t - off];
    nxt[t] = v;
    __syncthreads();
    int* tmp = cur; cur = nxt; nxt = tmp;
  }
  int excl = cur[t] - ssum;
  if (k0 < NBKT) starts[k0] = excl;
  if (k1 <= NBKT) starts[k1] = excl + tot0;             // t=781 writes starts[NBKT]=NE
}

// ---------------- pass B3: per-(block,bucket) bases (grid-parallel) ----------------
__global__ __launch_bounds__(256) void k_bases(int* __restrict__ bh,
                                               const int* __restrict__ starts) {
  int k = blockIdx.x * 256 + threadIdx.x;
  if (k >= NBKT) return;
  int run = starts[k];
  for (int b = 0; b < NB; ++b) {
    size_t idx = (size_t)b * NBKT + k;
    int v = bh[idx];
    bh[idx] = run;
    run += v;
  }
}

// ---------------- pass C: scatter edge ids into bucket order ----------------
__global__ __launch_bounds__(256) void k_scatter(const int* __restrict__ ei,
                                                 const int* __restrict__ bh,
                                                 int* __restrict__ perm) {
  __shared__ int base[NBKT];
  __shared__ int cnt[NBKT];
  const int* row = bh + (size_t)blockIdx.x * NBKT;
  for (int k = threadIdx.x; k < NBKT; k += 256) { base[k] = row[k]; cnt[k] = 0; }
  __syncthreads();
  const int* dstp = ei + NE;
  int s = blockIdx.x * CHUNK;
  for (int i = s + threadIdx.x; i < s + CHUNK; i += 256) {
    int d = dstp[i];
    int k = d >> 6;
    int r = atomicAdd(&cnt[k], 1);                      // LDS atomic
    perm[base[k] + r] = i | ((d & 63) << 24);           // edge id (21b) | dst-low6 <<24
  }
}

// ---------------- pass D: edge MLP + fused node MLP + graph pooling ----------------
// Lane (ep,jp): ep = edge slot (6/wave), jp = output pair (10). Lane holds
// W[k] = Wm[k][2jp..2jp+1] as pinned v2f (96 VGPRs) -> zero weight re-fetch.
// Next iteration's eattr + nattr[src] float4s are prefetched in the current
// body to hide the ~900-cyc HBM gather latency. dst-node loads stay direct
// (L1-hot: 64 nodes x 64 B per bucket). Epilogue: node MLP + LDS graph
// pre-aggregation (sorted batch), sparse global atomics to g.
#define PK4(V, K0) \
  a0 = __builtin_elementwise_fma(v2f{(V).x, (V).x}, W[K0+0], a0); \
  a1 = __builtin_elementwise_fma(v2f{(V).y, (V).y}, W[K0+1], a1); \
  a2 = __builtin_elementwise_fma(v2f{(V).z, (V).z}, W[K0+2], a2); \
  a3 = __builtin_elementwise_fma(v2f{(V).w, (V).w}, W[K0+3], a3);

__global__ __launch_bounds__(256, 2) void k_edge(
    const int* __restrict__ ei,
    const float* __restrict__ nattr,
    const float* __restrict__ eattr,
    const float* __restrict__ Wm,
    const float* __restrict__ bm,
    const int* __restrict__ batch,
    const float* __restrict__ W1,
    const float* __restrict__ b1,
    const int* __restrict__ perm,
    const int* __restrict__ starts,
    float* __restrict__ g) {
  __shared__ float xt[20 * 65];    // padded rows
  __shared__ float gb[64 * 10];    // graph partials for this bucket's span
  __shared__ int s_se[2];
  __shared__ int s_bmin;
  for (int i = threadIdx.x; i < 20 * 65; i += 256) xt[i] = 0.f;
  for (int i = threadIdx.x; i < 640; i += 256) gb[i] = 0.f;
  if (threadIdx.x < 2) s_se[threadIdx.x] = starts[blockIdx.x + threadIdx.x];
  int nbase = blockIdx.x * BKT;
  if (threadIdx.x == 0) s_bmin = batch[nbase];
  __syncthreads();
  int is = s_se[0], ie = s_se[1];

  int wave = threadIdx.x >> 6;
  int lane = threadIdx.x & 63;
  int ep = lane / 10;              // 0..6 (6 -> idle lane)
  int jp = lane - ep * 10;         // 0..9
  bool act = ep < 6;
  int epc = act ? ep : 0;

  v2f W[48];                       // resident weights: 96 VGPRs, pinned
#pragma unroll
  for (int k = 0; k < 48; ++k)
    W[k] = v2f{Wm[k * 20 + 2 * jp], Wm[k * 20 + 2 * jp + 1]};
#pragma unroll
  for (int k = 0; k < 48; ++k) asm volatile("" : "+v"(W[k]));
  v2f bj = {bm[2 * jp], bm[2 * jp + 1]};

  int base = is + wave * 6;
  int iC = base + epc;
  int pC = 0, sC = 0;
  float4 e0, e1, e2, e3, n0, n1, n2, n3;
  if (base < ie) {
    pC = perm[min(iC, ie - 1)];
    sC = ei[pC & 0xFFFFFF];
    const float4* pe = (const float4*)(eattr + (size_t)(pC & 0xFFFFFF) * 16);
    const float4* ps = (const float4*)(nattr + (size_t)sC * 16);
    e0 = pe[0]; e1 = pe[1]; e2 = pe[2]; e3 = pe[3];
    n0 = ps[0]; n1 = ps[1]; n2 = ps[2]; n3 = ps[3];
  }
  while (base < ie) {
    int baseN = base + 24;                              // 4 waves x 6 edges
    int iN = baseN + epc;
    int pN = 0, sN = 0;
    if (baseN < ie) {
      pN = perm[min(iN, ie - 1)];
      sN = ei[pN & 0xFFFFFF];
    }
    // prefetch next iteration's features (consumed next iter -> latency hidden)
    const float4* peN = (const float4*)(eattr + (size_t)(pN & 0xFFFFFF) * 16);
    const float4* psN = (const float4*)(nattr + (size_t)sN * 16);
    float4 e0N = peN[0], e1N = peN[1], e2N = peN[2], e3N = peN[3];
    float4 n0N = psN[0], n1N = psN[1], n2N = psN[2], n3N = psN[3];

    int dl = (pC >> 24) & 63;
    const float4* pd = (const float4*)(nattr + (size_t)(nbase + dl) * 16);
    float4 u0 = pd[0], u1 = pd[1], u2 = pd[2], u3 = pd[3];   // L1-hot

    v2f a0 = {0.f, 0.f}, a1 = {0.f, 0.f}, a2 = {0.f, 0.f}, a3 = {0.f, 0.f};
    PK4(n0, 0)  PK4(n1, 4)  PK4(n2, 8)  PK4(n3, 12)     // src feats
    PK4(u0, 16) PK4(u1, 20) PK4(u2, 24) PK4(u3, 28)     // dst feats
    PK4(e0, 32) PK4(e1, 36) PK4(e2, 40) PK4(e3, 44)     // edge feats
    v2f r = ((a0 + a1) + (a2 + a3)) + bj;

    bool valid = act && (iC < ie);
    float m0 = fmaxf(r.x, 0.f);
    float m1 = fmaxf(r.y, 0.f);
    if (valid && m0 > 0.f) atomicAdd(&xt[(2 * jp) * 65 + dl], m0);     // LDS
    if (valid && m1 > 0.f) atomicAdd(&xt[(2 * jp + 1) * 65 + dl], m1);

    base = baseN; iC = iN; pC = pN; sC = sN;
    e0 = e0N; e1 = e1N; e2 = e2N; e3 = e3N;
    n0 = n0N; n1 = n1N; n2 = n2N; n3 = n3N;
  }
  __syncthreads();

  // ---- fused node MLP (20 -> 10, relu) + graph pre-aggregation ----
  int nn = min(BKT, NN - nbase);
  int bmin = s_bmin;
  if (threadIdx.x < 64 && (int)threadIdx.x < nn) {
    int node = threadIdx.x;
    float xi[20];
#pragma unroll
    for (int j = 0; j < 20; ++j) xi[j] = xt[j * 65 + node];
    float acc[10];
#pragma unroll
    for (int j = 0; j < 10; ++j) acc[j] = b1[j];
#pragma unroll
    for (int k = 0; k < 20; ++k) {
      float fk = xi[k];
#pragma unroll
      for (int j = 0; j < 10; ++j) acc[j] = fmaf(fk, W1[k * 10 + j], acc[j]);
    }
    int bn = batch[nbase + node];
    int d = bn - bmin;                                  // >= 0 (batch sorted)
    if (d < 64) {
#pragma unroll
      for (int j = 0; j < 10; ++j) {
        float m = fmaxf(acc[j], 0.f);
        if (m > 0.f) atomicAdd(&gb[d * 10 + j], m);     // LDS
      }
    } else {                                            // rare large jump
#pragma unroll
      for (int j = 0; j < 10; ++j) {
        float m = fmaxf(acc[j], 0.f);
        if (m > 0.f) unsafeAtomicAdd(&g[(size_t)bn * 10 + j], m);
      }
    }
  }
  __syncthreads();
  int glim = min(640, NG * 10 - bmin * 10);
  float* gp = g + (size_t)bmin * 10;
  for (int idx = threadIdx.x; idx < glim; idx += 256) {
    float v = gb[idx];
    if (v != 0.f) unsafeAtomicAdd(&gp[idx], v);         // ~40 sparse atomics/block
  }
}

// ---------------- graph MLP ----------------
__global__ __launch_bounds__(256) void k_graph(
    const float* __restrict__ g,
    const float* __restrict__ W2, const float* __restrict__ b2,
    const float* __restrict__ W3, const float* __restrict__ b3,
    float* __restrict__ out) {
  int i = blockIdx.x * 256 + threadIdx.x;
  if (i >= NG) return;
  float gi[10];
  const float2* pg = (const float2*)(g + (size_t)i * 10);
#pragma unroll
  for (int k = 0; k < 5; ++k) { float2 v = pg[k]; gi[2*k] = v.x; gi[2*k+1] = v.y; }
  float o = b3[0];
#pragma unroll
  for (int j = 0; j < 10; ++j) {
    float a = b2[j];
#pragma unroll
    for (int k = 0; k < 10; ++k) a = fmaf(gi[k], W2[k * 10 + j], a);
    o = fmaf(fmaxf(a, 0.f), W3[j], o);
  }
  out[i] = o;
}

extern "C" void kernel_launch(void* const* d_in, const int* in_sizes, int n_in,
                              void* d_out, int out_size, void* d_ws, size_t ws_size,
                              hipStream_t stream) {
  const int*   ei    = (const int*)  d_in[0];
  const float* nattr = (const float*)d_in[1];
  const float* eattr = (const float*)d_in[2];
  const int*   batch = (const int*)  d_in[3];
  const float* Wm    = (const float*)d_in[4];
  const float* bm    = (const float*)d_in[5];
  const float* W1    = (const float*)d_in[6];
  const float* b1    = (const float*)d_in[7];
  const float* W2    = (const float*)d_in[8];
  const float* b2    = (const float*)d_in[9];
  const float* W3    = (const float*)d_in[10];
  const float* b3    = (const float*)d_in[11];

  float* g      = (float*)d_ws + OFF_G;
  int*   bh     = (int*)d_ws + OFF_BH;
  int*   starts = (int*)d_ws + OFF_ST;
  int*   perm   = (int*)d_ws + OFF_PM;

  constexpr int SCAN_BLKS = (NBKT + 255) / 256;   // 7

  k_hist   <<<NB, 256, 0, stream>>>(ei, bh, g);
  k_btot   <<<SCAN_BLKS, 256, 0, stream>>>(bh, starts);
  k_sscan  <<<1, 1024, 0, stream>>>(starts);
  k_bases  <<<SCAN_BLKS, 256, 0, stream>>>(bh, starts);
  k_scatter<<<NB, 256, 0, stream>>>(ei, bh, perm);
  k_edge   <<<NBKT, 256, 0, stream>>>(ei, nattr, eattr, Wm, bm, batch, W1, b1,
                                      perm, starts, g);
  k_graph  <<<(NG + 255) / 256, 256, 0, stream>>>(g, W2, b2, W3, b3, (float*)d_out);
}